// Round 7
// baseline (133.201 us; speedup 1.0000x reference)
//
#include <hip/hip_runtime.h>
#include <hip/hip_bf16.h>

#define NQ 16384
#define MM 2048
#define DD 128

typedef __attribute__((ext_vector_type(8))) short bf16x8;
typedef __attribute__((ext_vector_type(4))) float f32x4;
typedef __attribute__((ext_vector_type(16))) float f32x16;

#define MFMA16(a, b, c) __builtin_amdgcn_mfma_f32_16x16x32_bf16((a), (b), (c), 0, 0, 0)
#define MFMA32(a, b, c) __builtin_amdgcn_mfma_f32_32x32x16_bf16((a), (b), (c), 0, 0, 0)

static __device__ __forceinline__ unsigned short f2bf(float x) {
    union { __hip_bfloat16 h; unsigned short u; } cv;
    cv.h = __float2bfloat16(x);
    return cv.u;
}
static __device__ __forceinline__ unsigned pk2(float a, float b) {
    return (unsigned)f2bf(a) | ((unsigned)f2bf(b) << 16);
}
static __device__ __forceinline__ float bfl(unsigned u) {
    union { unsigned v; float f; } c; c.v = u << 16; return c.f;
}
static __device__ __forceinline__ float bfh(unsigned u) {
    union { unsigned v; float f; } c; c.v = u & 0xffff0000u; return c.f;
}
static __device__ __forceinline__ bf16x8 ldbf8(const unsigned short* p) {
    return *reinterpret_cast<const bf16x8*>(p);
}

union AW { unsigned u[4]; bf16x8 v; };

// ---------------------------------------------------------------------------
// K01: merged prep. blocks 0..31: normalize memory_index_w -> minn bf16 and
// transpose memory_w -> mwt bf16 [D][M], two m-rows per thread (4B stores).
// blocks 32..79: convert W_t / W_t2 -> bf16, float4-vectorized.
// ---------------------------------------------------------------------------
__global__ __launch_bounds__(256) void k01_prep(const float* __restrict__ miw,
                                                const float* __restrict__ mw,
                                                const float* __restrict__ wt,
                                                const float* __restrict__ wt2,
                                                unsigned short* __restrict__ minn,
                                                unsigned short* __restrict__ mwt,
                                                unsigned short* __restrict__ wtb,
                                                unsigned short* __restrict__ wt2b) {
    int b = blockIdx.x;
    if (b >= 32) {
        int i = (b - 32) * 1024 + threadIdx.x * 4;   // 48 blocks cover 49152
        if (i < DD * DD) {
            float4 x = *reinterpret_cast<const float4*>(wt + i);
            uint2 u = make_uint2(pk2(x.x, x.y), pk2(x.z, x.w));
            *reinterpret_cast<uint2*>(wtb + i) = u;
        } else {
            int j = i - DD * DD;
            float4 x = *reinterpret_cast<const float4*>(wt2 + j);
            uint2 u = make_uint2(pk2(x.x, x.y), pk2(x.z, x.w));
            *reinterpret_cast<uint2*>(wt2b + j) = u;
        }
        return;
    }
    int t = threadIdx.x;
    int pr = t >> 3;             // row-pair index 0..31
    int e = t & 7;               // column eighth (16 cols)
    int m0 = b * 64 + pr * 2;    // even m row

    float v0[16], v1[16];
    float ss0 = 0.f, ss1 = 0.f;
#pragma unroll
    for (int k = 0; k < 4; ++k) {
        float4 x = reinterpret_cast<const float4*>(miw + m0 * DD + e * 16)[k];
        v0[4 * k] = x.x; v0[4 * k + 1] = x.y; v0[4 * k + 2] = x.z; v0[4 * k + 3] = x.w;
        ss0 += x.x * x.x + x.y * x.y + x.z * x.z + x.w * x.w;
        float4 y = reinterpret_cast<const float4*>(miw + (m0 + 1) * DD + e * 16)[k];
        v1[4 * k] = y.x; v1[4 * k + 1] = y.y; v1[4 * k + 2] = y.z; v1[4 * k + 3] = y.w;
        ss1 += y.x * y.x + y.y * y.y + y.z * y.z + y.w * y.w;
    }
    ss0 += __shfl_xor(ss0, 1); ss0 += __shfl_xor(ss0, 2); ss0 += __shfl_xor(ss0, 4);
    ss1 += __shfl_xor(ss1, 1); ss1 += __shfl_xor(ss1, 2); ss1 += __shfl_xor(ss1, 4);
    float sc0 = 1.0f / fmaxf(sqrtf(ss0), 1e-8f);
    float sc1 = 1.0f / fmaxf(sqrtf(ss1), 1e-8f);

    unsigned* d0 = reinterpret_cast<unsigned*>(minn + m0 * DD + e * 16);
    unsigned* d1 = reinterpret_cast<unsigned*>(minn + (m0 + 1) * DD + e * 16);
#pragma unroll
    for (int k = 0; k < 8; ++k) {
        d0[k] = pk2(v0[2 * k] * sc0, v0[2 * k + 1] * sc0);
        d1[k] = pk2(v1[2 * k] * sc1, v1[2 * k + 1] * sc1);
    }

    float w0[16], w1[16];
#pragma unroll
    for (int k = 0; k < 4; ++k) {
        float4 x = reinterpret_cast<const float4*>(mw + m0 * DD + e * 16)[k];
        w0[4 * k] = x.x; w0[4 * k + 1] = x.y; w0[4 * k + 2] = x.z; w0[4 * k + 3] = x.w;
        float4 y = reinterpret_cast<const float4*>(mw + (m0 + 1) * DD + e * 16)[k];
        w1[4 * k] = y.x; w1[4 * k + 1] = y.y; w1[4 * k + 2] = y.z; w1[4 * k + 3] = y.w;
    }
#pragma unroll
    for (int k = 0; k < 16; ++k)
        *reinterpret_cast<unsigned*>(mwt + (e * 16 + k) * MM + m0) = pk2(w0[k], w1[k]);
}

// ---------------------------------------------------------------------------
// K3: fully fused transform + attention + gating.
// Grid 256 x 1024thr (1 block/CU, 16 waves). Block = one 64-query strip.
// Wave = (q-half qh, m-eighth me8): 32 q x 256 m, 8 iters of 32 m.
// Per-block m-phase ROTATION (rot = (bid>>3)&7) decorrelates the address
// streams of different blocks to kill the L2 same-line hotspot.
// minn tiles staged per-eighth to LDS via global_load_lds (double-buffered,
// source-XOR-swizzled); one s_barrier + vmcnt(4) per iter.
// Epilogue: bf16 LDS reduction across the 8 m-eighths, then fused gating.
// ---------------------------------------------------------------------------
__global__ __launch_bounds__(1024) void k3_fused(const float* __restrict__ query,
                                                 const unsigned short* __restrict__ wtb,
                                                 const float* __restrict__ bt,
                                                 const unsigned short* __restrict__ minn,
                                                 const unsigned short* __restrict__ mwt,
                                                 const unsigned short* __restrict__ wt2b,
                                                 const float* __restrict__ bt2,
                                                 float* __restrict__ me_out,
                                                 float* __restrict__ out) {
    // [0,131072):  staging, buf b at b*65536, eighth me8 at +me8*8192
    //              (post-loop: 14 reduction slots of 8704 B, aliased)
    // [131072,148480): tqm 64 rows x 136 shorts (tq_n, later me tile)
    __shared__ __align__(16) char pool[148480];
    unsigned short* tqm = reinterpret_cast<unsigned short*>(pool + 131072);

    const int lane = threadIdx.x & 63;
    const int wid = threadIdx.x >> 6;   // 0..15
    const int qh = wid & 1;             // q-half (32 q)
    const int me8 = wid >> 1;           // m-eighth (256 m)
    const int ml = lane & 31;
    const int hi = lane >> 5;
    const int n0 = blockIdx.x * 64;
    const int rot = (blockIdx.x >> 3) & 7;
    const float L2E = 1.44269504088896340736f;

    // stage 16 rows (this wave's half) of eighth me8's 32-row tile `ti`.
    // LDS dest linear; global source column XOR-swizzled by (row&15)<<4.
    auto stage = [&](int ti, int b) {
#pragma unroll
        for (int k = 0; k < 4; ++k) {
            int row = 16 * qh + 4 * k + (lane >> 4);          // 0..31
            int scol = ((lane & 15) * 16) ^ ((row & 15) << 4);
            const unsigned short* src = minn + (me8 * 256 + ti * 32 + row) * DD + scol / 2;
            __builtin_amdgcn_global_load_lds(
                (const __attribute__((address_space(1))) unsigned int*)src,
                (__attribute__((address_space(3))) unsigned int*)
                    (pool + b * 65536 + me8 * 8192 + (16 * qh + 4 * k) * 256),
                16, 0, 0);
        }
    };

    // prestage iteration-0 tile into buf 0 (lands under phase-0 compute)
    stage(rot, 0);

    // ---- Phase 0: transform 64 q (waves 0..3, 16 q each), tq pre-scaled L2E
    if (wid < 4) {
        const int nl = lane & 15;
        const int g = lane >> 4;
        const int qb = n0 + 16 * wid;
        AW aq[4];
#pragma unroll
        for (int c = 0; c < 4; ++c) {
            const float* p = query + (qb + nl) * DD + 32 * c + 8 * g;
            float4 x0 = reinterpret_cast<const float4*>(p)[0];
            float4 x1 = reinterpret_cast<const float4*>(p)[1];
            aq[c].u[0] = pk2(x0.x, x0.y); aq[c].u[1] = pk2(x0.z, x0.w);
            aq[c].u[2] = pk2(x1.x, x1.y); aq[c].u[3] = pk2(x1.z, x1.w);
        }
        f32x4 acc[8];
#pragma unroll
        for (int t = 0; t < 8; ++t) acc[t] = (f32x4){0.f, 0.f, 0.f, 0.f};
#pragma unroll
        for (int t = 0; t < 8; ++t)
#pragma unroll
            for (int c = 0; c < 4; ++c) {
                bf16x8 bv = ldbf8(wtb + (16 * t + nl) * DD + 32 * c + 8 * g);
                acc[t] = MFMA16(aq[c].v, bv, acc[t]);
            }
        float ss[4] = {0.f, 0.f, 0.f, 0.f};
#pragma unroll
        for (int t = 0; t < 8; ++t) {
            float bias = bt[16 * t + nl];
#pragma unroll
            for (int r = 0; r < 4; ++r) {
                float v = acc[t][r] + bias;
                acc[t][r] = v;
                ss[r] += v * v;
            }
        }
#pragma unroll
        for (int r = 0; r < 4; ++r) {
            ss[r] += __shfl_xor(ss[r], 1);
            ss[r] += __shfl_xor(ss[r], 2);
            ss[r] += __shfl_xor(ss[r], 4);
            ss[r] += __shfl_xor(ss[r], 8);
        }
        float scl[4];
#pragma unroll
        for (int r = 0; r < 4; ++r) scl[r] = L2E / fmaxf(sqrtf(ss[r]), 1e-8f);
#pragma unroll
        for (int t = 0; t < 8; ++t)
#pragma unroll
            for (int r = 0; r < 4; ++r)
                tqm[(16 * wid + 4 * g + r) * 136 + 16 * t + nl] = f2bf(acc[t][r] * scl[r]);
    }
    asm volatile("s_waitcnt vmcnt(0)" ::: "memory");  // tile-0 DMA landed
    __syncthreads();                                  // + tq visible

    // Qn B-fragments for this wave's q-half (col n = ml, k = d)
    bf16x8 qn[8];
#pragma unroll
    for (int c = 0; c < 8; ++c)
        qn[c] = *reinterpret_cast<const bf16x8*>(&tqm[(32 * qh + ml) * 136 + 16 * c + 8 * hi]);

    const f32x16 zero16 = {0.f,0.f,0.f,0.f,0.f,0.f,0.f,0.f,0.f,0.f,0.f,0.f,0.f,0.f,0.f,0.f};
    f32x16 o[4];
#pragma unroll
    for (int t = 0; t < 4; ++t) o[t] = zero16;
    float den = 0.0f;

#pragma unroll 2
    for (int it = 0; it < 8; ++it) {
        const int tb = it & 1;
        if (it < 7) {
            stage((it + 1 + rot) & 7, tb ^ 1);
            asm volatile("s_waitcnt vmcnt(4)" ::: "memory");  // tile `it` landed
        } else {
            asm volatile("s_waitcnt vmcnt(0)" ::: "memory");
        }
        __builtin_amdgcn_sched_barrier(0);
        __builtin_amdgcn_s_barrier();      // all waves' halves of tile `it` in
        __builtin_amdgcn_sched_barrier(0);

        const int ti = (it + rot) & 7;

        // QK A-frags from this eighth's swizzled LDS tile (row = ml)
        const char* arow = pool + tb * 65536 + me8 * 8192 + ml * 256;
        bf16x8 aA[8];
#pragma unroll
        for (int c = 0; c < 8; ++c)
            aA[c] = *reinterpret_cast<const bf16x8*>(
                arow + ((32 * c + 16 * hi) ^ ((ml & 15) << 4)));

        f32x16 sA = zero16, sB = zero16;
#pragma unroll
        for (int c = 0; c < 4; ++c) sA = MFMA32(aA[c], qn[c], sA);
#pragma unroll
        for (int c = 4; c < 8; ++c) sB = MFMA32(aA[c], qn[c], sB);

        // PV B-frags direct from global mwt[d][m]
        const int m0 = me8 * 256 + ti * 32;
        bf16x8 bw[8];
#pragma unroll
        for (int dt = 0; dt < 4; ++dt)
#pragma unroll
            for (int kc = 0; kc < 2; ++kc)
                bw[dt * 2 + kc] = ldbf8(mwt + (32 * dt + ml) * MM + m0 + 16 * kc + 8 * hi);

        float p[16];
#pragma unroll
        for (int r = 0; r < 16; ++r)
            p[r] = __builtin_amdgcn_exp2f(sA[r] + sB[r]);
        {
            float e0 = (p[0] + p[1]) + (p[2] + p[3]);
            float e1 = (p[4] + p[5]) + (p[6] + p[7]);
            float e2 = (p[8] + p[9]) + (p[10] + p[11]);
            float e3 = (p[12] + p[13]) + (p[14] + p[15]);
            den += (e0 + e1) + (e2 + e3);
        }
        unsigned w0 = pk2(p[0], p[1]),   w1 = pk2(p[2], p[3]);
        unsigned w2 = pk2(p[4], p[5]),   w3 = pk2(p[6], p[7]);
        unsigned w4 = pk2(p[8], p[9]),   w5 = pk2(p[10], p[11]);
        unsigned w6 = pk2(p[12], p[13]), w7 = pk2(p[14], p[15]);
        auto r02 = __builtin_amdgcn_permlane32_swap(w0, w2, false, false);
        auto r13 = __builtin_amdgcn_permlane32_swap(w1, w3, false, false);
        auto r46 = __builtin_amdgcn_permlane32_swap(w4, w6, false, false);
        auto r57 = __builtin_amdgcn_permlane32_swap(w5, w7, false, false);
        AW a0, a1;
        a0.u[0] = r02[0]; a0.u[1] = r13[0]; a0.u[2] = r02[1]; a0.u[3] = r13[1];
        a1.u[0] = r46[0]; a1.u[1] = r57[0]; a1.u[2] = r46[1]; a1.u[3] = r57[1];
#pragma unroll
        for (int dt = 0; dt < 4; ++dt) {
            o[dt] = MFMA32(a0.v, bw[dt * 2 + 0], o[dt]);
            o[dt] = MFMA32(a1.v, bw[dt * 2 + 1], o[dt]);
        }
    }

    // ---- cross-eighth reduction (bf16 partials aliased into staging) ----
    __syncthreads();  // everyone done reading staging buffers
    if (me8 >= 1) {
        char* dst = pool + ((me8 - 1) + 7 * qh) * 8704 + lane * 136;
#pragma unroll
        for (int t = 0; t < 4; ++t) {
            unsigned u[8];
#pragma unroll
            for (int k = 0; k < 8; ++k) u[k] = pk2(o[t][2 * k], o[t][2 * k + 1]);
            *reinterpret_cast<uint4*>(dst + t * 32) = make_uint4(u[0], u[1], u[2], u[3]);
            *reinterpret_cast<uint4*>(dst + t * 32 + 16) = make_uint4(u[4], u[5], u[6], u[7]);
        }
        *reinterpret_cast<float*>(dst + 128) = den;
    }
    __syncthreads();
    if (me8 == 0) {  // waves 0 (qh=0) and 1 (qh=1)
        for (int s = 0; s < 7; ++s) {
            const char* src = pool + (s + 7 * qh) * 8704 + lane * 136;
#pragma unroll
            for (int t = 0; t < 4; ++t) {
                uint4 ua = *reinterpret_cast<const uint4*>(src + t * 32);
                uint4 ub = *reinterpret_cast<const uint4*>(src + t * 32 + 16);
                unsigned u[8] = {ua.x, ua.y, ua.z, ua.w, ub.x, ub.y, ub.z, ub.w};
#pragma unroll
                for (int k = 0; k < 8; ++k) {
                    o[t][2 * k] += bfl(u[k]);
                    o[t][2 * k + 1] += bfh(u[k]);
                }
            }
            den += *reinterpret_cast<const float*>(src + 128);
        }
        den += __shfl_xor(den, 32);
        float invd = 1.0f / den;
        float inv[16];
#pragma unroll
        for (int r = 0; r < 16; ++r)
            inv[r] = __shfl(invd, (r & 3) + 8 * (r >> 2) + 4 * hi);
#pragma unroll
        for (int t = 0; t < 4; ++t)
#pragma unroll
            for (int r = 0; r < 16; ++r) {
                int row = (r & 3) + 8 * (r >> 2) + 4 * hi;
                float me = o[t][r] * inv[r];
                me_out[(n0 + 32 * qh + row) * DD + 32 * t + ml] = me;
                tqm[(32 * qh + row) * 136 + 32 * t + ml] = f2bf(me);
            }
    }
    __syncthreads();

    // ---- fused gating: G = tanh(cat(me,q) @ W_t2^T + b_t2); blend ----
    if (wid < 8) {
        const int qg = wid & 1;   // q-half
        const int dt = wid >> 1;  // d-tile 32*dt .. 32*dt+31
        f32x16 g = zero16;
#pragma unroll
        for (int c = 0; c < 8; ++c) {  // k < 128: me from LDS tile
            bf16x8 av = *reinterpret_cast<const bf16x8*>(
                &tqm[(32 * qg + ml) * 136 + 16 * c + 8 * hi]);
            bf16x8 bv = ldbf8(wt2b + (32 * dt + ml) * 256 + 16 * c + 8 * hi);
            g = MFMA32(av, bv, g);
        }
#pragma unroll
        for (int c = 8; c < 16; ++c) {  // k >= 128: query from global
            const float* p = query + (n0 + 32 * qg + ml) * DD + 16 * (c - 8) + 8 * hi;
            float4 x0 = reinterpret_cast<const float4*>(p)[0];
            float4 x1 = reinterpret_cast<const float4*>(p)[1];
            AW av;
            av.u[0] = pk2(x0.x, x0.y); av.u[1] = pk2(x0.z, x0.w);
            av.u[2] = pk2(x1.x, x1.y); av.u[3] = pk2(x1.z, x1.w);
            bf16x8 bv = ldbf8(wt2b + (32 * dt + ml) * 256 + 16 * c + 8 * hi);
            g = MFMA32(av.v, bv, g);
        }
        const float TWO_L2E = 2.88539008177792681472f;  // 2*log2(e)
        const int d = 32 * dt + ml;
        const float bias = bt2[d];
#pragma unroll
        for (int r = 0; r < 16; ++r) {
            int row = 32 * qg + (r & 3) + 8 * (r >> 2) + 4 * hi;
            float x = g[r] + bias;
            float gt = 1.0f - 2.0f / (__builtin_amdgcn_exp2f(x * TWO_L2E) + 1.0f);
            float qv = query[(n0 + row) * DD + d];
            float mv = bfl(tqm[row * 136 + d]);
            out[(n0 + row) * DD + d] = qv + gt * (mv - qv);
        }
    }
}

// ---------------------------------------------------------------------------
extern "C" void kernel_launch(void* const* d_in, const int* in_sizes, int n_in,
                              void* d_out, int out_size, void* d_ws, size_t ws_size,
                              hipStream_t stream) {
    const float* query = (const float*)d_in[0];   // [N,128]
    const float* wt    = (const float*)d_in[1];   // [128,128]
    const float* bt    = (const float*)d_in[2];   // [128]
    const float* miw   = (const float*)d_in[3];   // [M,128]
    const float* mw    = (const float*)d_in[4];   // [M,128]
    const float* wt2   = (const float*)d_in[5];   // [128,256]
    const float* bt2   = (const float*)d_in[6];   // [128]

    float* out    = (float*)d_out;                // output 0: [N,128]
    float* me_out = out + (size_t)NQ * DD;        // output 1: mem_emb [N,128]

    // workspace layout (bf16 arrays), ~1.2 MB total
    unsigned short* minn = (unsigned short*)d_ws;          // [M][128]
    unsigned short* mwt  = minn + (size_t)MM * DD;         // [128][M]
    unsigned short* wtb  = mwt + (size_t)DD * MM;          // [128][128]
    unsigned short* wt2b = wtb + (size_t)DD * DD;          // [128][256]

    k01_prep<<<80, 256, 0, stream>>>(miw, mw, wt, wt2, minn, mwt, wtb, wt2b);
    k3_fused<<<NQ / 64, 1024, 0, stream>>>(query, wtb, bt, minn, mwt, wt2b, bt2,
                                           me_out, out);
}

// Round 8
// 48.108 us; speedup vs baseline: 2.7688x; 2.7688x over previous
//
#include <hip/hip_runtime.h>
#include <hip/hip_bf16.h>

#define NQ 16384
#define MM 2048
#define DD 128

typedef __attribute__((ext_vector_type(8))) short bf16x8;
typedef __attribute__((ext_vector_type(4))) float f32x4;
typedef __attribute__((ext_vector_type(16))) float f32x16;

#define MFMA16(a, b, c) __builtin_amdgcn_mfma_f32_16x16x32_bf16((a), (b), (c), 0, 0, 0)
#define MFMA32(a, b, c) __builtin_amdgcn_mfma_f32_32x32x16_bf16((a), (b), (c), 0, 0, 0)

static __device__ __forceinline__ unsigned short f2bf(float x) {
    union { __hip_bfloat16 h; unsigned short u; } cv;
    cv.h = __float2bfloat16(x);
    return cv.u;
}
static __device__ __forceinline__ unsigned pk2(float a, float b) {
    return (unsigned)f2bf(a) | ((unsigned)f2bf(b) << 16);
}
static __device__ __forceinline__ float bfl(unsigned u) {
    union { unsigned v; float f; } c; c.v = u << 16; return c.f;
}
static __device__ __forceinline__ float bfh(unsigned u) {
    union { unsigned v; float f; } c; c.v = u & 0xffff0000u; return c.f;
}
static __device__ __forceinline__ bf16x8 ldbf8(const unsigned short* p) {
    return *reinterpret_cast<const bf16x8*>(p);
}

union AW { unsigned u[4]; bf16x8 v; };

// ---------------------------------------------------------------------------
// K01: prep with FRAGMENT-ORDER packing.
// blocks 0..63 (one 32-m tile each): normalize memory_index_w rows and pack
//   into minnA[(tile*8+c)*64 + lane][8]  = minn[tile*32 + (lane&31)][16c + 8*(lane>>5) + j]
//   pack memory_w into
//   mwB[(tile*8+kc*4+dt)*64 + lane][8]   = mw[tile*32 + 16kc + 8*(lane>>5) + j][32dt + (lane&31)]
// blocks 64..111: W_t -> wtb (row-major bf16);
//   W_t2 -> wt2f[(c*4+dt)*64 + lane][8]  = wt2[32dt + (lane&31)][16c + 8*(lane>>5) + j]
// ---------------------------------------------------------------------------
__global__ __launch_bounds__(256) void k01_prep(const float* __restrict__ miw,
                                                const float* __restrict__ mw,
                                                const float* __restrict__ wt,
                                                const float* __restrict__ wt2,
                                                unsigned short* __restrict__ minnA,
                                                unsigned short* __restrict__ mwB,
                                                unsigned short* __restrict__ wtb,
                                                unsigned short* __restrict__ wt2f) {
    int b = blockIdx.x;
    int t = threadIdx.x;
    if (b >= 64) {
        int i = (b - 64) * 1024 + t * 4;   // 48 blocks cover 49152 elems
        if (i < DD * DD) {
            float4 x = *reinterpret_cast<const float4*>(wt + i);
            *reinterpret_cast<uint2*>(wtb + i) = make_uint2(pk2(x.x, x.y), pk2(x.z, x.w));
        } else {
            int j = i - DD * DD;           // index into wt2 [128][256]
            float4 x = *reinterpret_cast<const float4*>(wt2 + j);
            int row = j >> 8, col = j & 255;
            unsigned short* dst = wt2f +
                (((((col >> 4) * 4 + (row >> 5)) * 64) + ((col >> 3) & 1) * 32 + (row & 31)) << 3) +
                (col & 7);
            dst[0] = f2bf(x.x); dst[1] = f2bf(x.y); dst[2] = f2bf(x.z); dst[3] = f2bf(x.w);
        }
        return;
    }
    int r = t >> 3;              // tile row 0..31
    int e = t & 7;               // 16-col group 0..7
    int m = b * 32 + r;

    // --- memory_index_w: load 16 cols, row-norm across the 8 e-threads ---
    float v[16];
    float ss = 0.f;
#pragma unroll
    for (int k = 0; k < 4; ++k) {
        float4 x = reinterpret_cast<const float4*>(miw + m * DD + e * 16)[k];
        v[4 * k] = x.x; v[4 * k + 1] = x.y; v[4 * k + 2] = x.z; v[4 * k + 3] = x.w;
        ss += x.x * x.x + x.y * x.y + x.z * x.z + x.w * x.w;
    }
    ss += __shfl_xor(ss, 1); ss += __shfl_xor(ss, 2); ss += __shfl_xor(ss, 4);
    float sc = 1.0f / fmaxf(sqrtf(ss), 1e-8f);

    // pack minnA: (c=e, hi=u>>3, j=u&7), two 16B stores
    unsigned u0 = pk2(v[0] * sc, v[1] * sc), u1 = pk2(v[2] * sc, v[3] * sc);
    unsigned u2 = pk2(v[4] * sc, v[5] * sc), u3 = pk2(v[6] * sc, v[7] * sc);
    unsigned u4 = pk2(v[8] * sc, v[9] * sc), u5 = pk2(v[10] * sc, v[11] * sc);
    unsigned u6 = pk2(v[12] * sc, v[13] * sc), u7 = pk2(v[14] * sc, v[15] * sc);
    *reinterpret_cast<uint4*>(minnA + ((((b * 8 + e) * 64) + r) << 3)) = make_uint4(u0, u1, u2, u3);
    *reinterpret_cast<uint4*>(minnA + ((((b * 8 + e) * 64) + 32 + r) << 3)) = make_uint4(u4, u5, u6, u7);

    // --- memory_w: pack into mwB fragment order ---
    float w[16];
#pragma unroll
    for (int k = 0; k < 4; ++k) {
        float4 x = reinterpret_cast<const float4*>(mw + m * DD + e * 16)[k];
        w[4 * k] = x.x; w[4 * k + 1] = x.y; w[4 * k + 2] = x.z; w[4 * k + 3] = x.w;
    }
    int kc = r >> 4, hh = (r >> 3) & 1, jj = r & 7;
    unsigned short* base = mwB +
        ((((b * 8 + kc * 4 + (e >> 1)) * 64) + hh * 32 + (e & 1) * 16) << 3) + jj;
#pragma unroll
    for (int u = 0; u < 16; ++u) base[u << 3] = f2bf(w[u]);
}

// ---------------------------------------------------------------------------
// K3: fused transform + attention + gating.  Dense-stream main loop:
// Grid 512 x 256thr. Block = one 32-query strip; wave w = m-quarter
// (16 tiles of 32 m).  Both operand streams pre-packed in fragment order ->
// every load is ldbf8(base + lane*8): 1KB dense per instruction.  Register
// double-buffer (unroll 2, compile-time indices), no LDS/barriers in loop.
// Per-block tile rotation decorrelates block address streams.
// Epilogue: bf16 LDS reduction across waves, then fused gating GEMM.
// ---------------------------------------------------------------------------
__global__ __launch_bounds__(256, 2) void k3_fused(const float* __restrict__ query,
                                                   const unsigned short* __restrict__ wtb,
                                                   const float* __restrict__ bt,
                                                   const unsigned short* __restrict__ minnA,
                                                   const unsigned short* __restrict__ mwB,
                                                   const unsigned short* __restrict__ wt2f,
                                                   const float* __restrict__ bt2,
                                                   float* __restrict__ me_out,
                                                   float* __restrict__ out) {
    // [0,26112): 3 reduction slots of 8704 B ; [26112,34816): tqm 32x136 shorts
    __shared__ __align__(16) char pool[34816];
    unsigned short* tqm = reinterpret_cast<unsigned short*>(pool + 26112);

    const int lane = threadIdx.x & 63;
    const int wid = threadIdx.x >> 6;   // m-quarter
    const int ml = lane & 31;
    const int hi = lane >> 5;
    const int n0 = blockIdx.x * 32;
    const float L2E = 1.44269504088896340736f;

    // ---- Phase 0: transform 32 q (waves 0,1; 16x16 path), tq pre-scaled L2E
    if (wid < 2) {
        const int nl = lane & 15;
        const int g = lane >> 4;
        const int qb = n0 + 16 * wid;
        AW aq[4];
#pragma unroll
        for (int c = 0; c < 4; ++c) {
            const float* p = query + (qb + nl) * DD + 32 * c + 8 * g;
            float4 x0 = reinterpret_cast<const float4*>(p)[0];
            float4 x1 = reinterpret_cast<const float4*>(p)[1];
            aq[c].u[0] = pk2(x0.x, x0.y); aq[c].u[1] = pk2(x0.z, x0.w);
            aq[c].u[2] = pk2(x1.x, x1.y); aq[c].u[3] = pk2(x1.z, x1.w);
        }
        f32x4 acc[8];
#pragma unroll
        for (int t = 0; t < 8; ++t) acc[t] = (f32x4){0.f, 0.f, 0.f, 0.f};
#pragma unroll
        for (int t = 0; t < 8; ++t)
#pragma unroll
            for (int c = 0; c < 4; ++c) {
                bf16x8 bv = ldbf8(wtb + (16 * t + nl) * DD + 32 * c + 8 * g);
                acc[t] = MFMA16(aq[c].v, bv, acc[t]);
            }
        float ss[4] = {0.f, 0.f, 0.f, 0.f};
#pragma unroll
        for (int t = 0; t < 8; ++t) {
            float bias = bt[16 * t + nl];
#pragma unroll
            for (int r = 0; r < 4; ++r) {
                float vv = acc[t][r] + bias;
                acc[t][r] = vv;
                ss[r] += vv * vv;
            }
        }
#pragma unroll
        for (int r = 0; r < 4; ++r) {
            ss[r] += __shfl_xor(ss[r], 1);
            ss[r] += __shfl_xor(ss[r], 2);
            ss[r] += __shfl_xor(ss[r], 4);
            ss[r] += __shfl_xor(ss[r], 8);
        }
        float scl[4];
#pragma unroll
        for (int r = 0; r < 4; ++r) scl[r] = L2E / fmaxf(sqrtf(ss[r]), 1e-8f);
#pragma unroll
        for (int t = 0; t < 8; ++t)
#pragma unroll
            for (int r = 0; r < 4; ++r)
                tqm[(16 * wid + 4 * g + r) * 136 + 16 * t + nl] = f2bf(acc[t][r] * scl[r]);
    }
    __syncthreads();  // tq visible to all waves

    // Qn B-fragments (col n = ml, k = d)
    bf16x8 qn[8];
#pragma unroll
    for (int c = 0; c < 8; ++c)
        qn[c] = *reinterpret_cast<const bf16x8*>(&tqm[ml * 136 + 16 * c + 8 * hi]);

    const f32x16 zero16 = {0.f,0.f,0.f,0.f,0.f,0.f,0.f,0.f,0.f,0.f,0.f,0.f,0.f,0.f,0.f,0.f};
    f32x16 o[4];
#pragma unroll
    for (int t = 0; t < 4; ++t) o[t] = zero16;
    float den = 0.0f;

    const int mt0 = wid * 16;            // this wave's 16-tile range
    const int rot = blockIdx.x & 15;

    bf16x8 aA[2][8], bw[2][8];
    {   // prologue: tile for it=0
        int ti = mt0 + rot;
#pragma unroll
        for (int c = 0; c < 8; ++c) aA[0][c] = ldbf8(minnA + ((ti * 8 + c) * 64 + lane) * 8);
#pragma unroll
        for (int q = 0; q < 8; ++q) bw[0][q] = ldbf8(mwB + ((ti * 8 + q) * 64 + lane) * 8);
    }

#pragma unroll 2
    for (int it = 0; it < 16; ++it) {
        const int cur = it & 1;
        // prefetch next tile's fragments (dense 1KB loads, independent regs)
        if (it < 15) {
            int tn = mt0 + ((it + 1 + rot) & 15);
#pragma unroll
            for (int c = 0; c < 8; ++c)
                aA[cur ^ 1][c] = ldbf8(minnA + ((tn * 8 + c) * 64 + lane) * 8);
#pragma unroll
            for (int q = 0; q < 8; ++q)
                bw[cur ^ 1][q] = ldbf8(mwB + ((tn * 8 + q) * 64 + lane) * 8);
        }

        // QK^T: D[m][n], two 4-deep accumulate chains over d
        f32x16 sA = zero16, sB = zero16;
#pragma unroll
        for (int c = 0; c < 4; ++c) sA = MFMA32(aA[cur][c], qn[c], sA);
#pragma unroll
        for (int c = 4; c < 8; ++c) sB = MFMA32(aA[cur][c], qn[c], sB);

        float p[16];
#pragma unroll
        for (int r = 0; r < 16; ++r)
            p[r] = __builtin_amdgcn_exp2f(sA[r] + sB[r]);
        {
            float e0 = (p[0] + p[1]) + (p[2] + p[3]);
            float e1 = (p[4] + p[5]) + (p[6] + p[7]);
            float e2 = (p[8] + p[9]) + (p[10] + p[11]);
            float e3 = (p[12] + p[13]) + (p[14] + p[15]);
            den += (e0 + e1) + (e2 + e3);
        }
        unsigned w0 = pk2(p[0], p[1]),   w1 = pk2(p[2], p[3]);
        unsigned w2 = pk2(p[4], p[5]),   w3 = pk2(p[6], p[7]);
        unsigned w4 = pk2(p[8], p[9]),   w5 = pk2(p[10], p[11]);
        unsigned w6 = pk2(p[12], p[13]), w7 = pk2(p[14], p[15]);
        auto r02 = __builtin_amdgcn_permlane32_swap(w0, w2, false, false);
        auto r13 = __builtin_amdgcn_permlane32_swap(w1, w3, false, false);
        auto r46 = __builtin_amdgcn_permlane32_swap(w4, w6, false, false);
        auto r57 = __builtin_amdgcn_permlane32_swap(w5, w7, false, false);
        AW a0, a1;
        a0.u[0] = r02[0]; a0.u[1] = r13[0]; a0.u[2] = r02[1]; a0.u[3] = r13[1];
        a1.u[0] = r46[0]; a1.u[1] = r57[0]; a1.u[2] = r46[1]; a1.u[3] = r57[1];
        // PV: a0 pairs kc=0 (bw[0..3] = dt 0..3), a1 pairs kc=1 (bw[4..7])
#pragma unroll
        for (int dt = 0; dt < 4; ++dt) {
            o[dt] = MFMA32(a0.v, bw[cur][dt], o[dt]);
            o[dt] = MFMA32(a1.v, bw[cur][4 + dt], o[dt]);
        }
    }

    // ---- cross-wave reduction (bf16 partials + f32 den) ----
    if (wid >= 1) {
        char* dst = pool + (wid - 1) * 8704 + lane * 136;
#pragma unroll
        for (int t = 0; t < 4; ++t) {
            unsigned u[8];
#pragma unroll
            for (int k = 0; k < 8; ++k) u[k] = pk2(o[t][2 * k], o[t][2 * k + 1]);
            *reinterpret_cast<uint4*>(dst + t * 32) = make_uint4(u[0], u[1], u[2], u[3]);
            *reinterpret_cast<uint4*>(dst + t * 32 + 16) = make_uint4(u[4], u[5], u[6], u[7]);
        }
        *reinterpret_cast<float*>(dst + 128) = den;
    }
    __syncthreads();
    if (wid == 0) {
        for (int s = 0; s < 3; ++s) {
            const char* src = pool + s * 8704 + lane * 136;
#pragma unroll
            for (int t = 0; t < 4; ++t) {
                uint4 ua = *reinterpret_cast<const uint4*>(src + t * 32);
                uint4 ub = *reinterpret_cast<const uint4*>(src + t * 32 + 16);
                unsigned u[8] = {ua.x, ua.y, ua.z, ua.w, ub.x, ub.y, ub.z, ub.w};
#pragma unroll
                for (int k = 0; k < 8; ++k) {
                    o[t][2 * k] += bfl(u[k]);
                    o[t][2 * k + 1] += bfh(u[k]);
                }
            }
            den += *reinterpret_cast<const float*>(src + 128);
        }
        den += __shfl_xor(den, 32);
        float invd = 1.0f / den;
        float inv[16];
#pragma unroll
        for (int r = 0; r < 16; ++r)
            inv[r] = __shfl(invd, (r & 3) + 8 * (r >> 2) + 4 * hi);
#pragma unroll
        for (int t = 0; t < 4; ++t)
#pragma unroll
            for (int r = 0; r < 16; ++r) {
                int row = (r & 3) + 8 * (r >> 2) + 4 * hi;
                float me = o[t][r] * inv[r];
                me_out[(n0 + row) * DD + 32 * t + ml] = me;
                tqm[row * 136 + 32 * t + ml] = f2bf(me);  // me tile for gating
            }
    }
    __syncthreads();

    // ---- fused gating: G = tanh(cat(me,q) @ W_t2^T + b_t2); blend ----
    {
        const int dt = wid;  // d-tile 32*dt .. 32*dt+31
        f32x16 g = zero16;
#pragma unroll
        for (int c = 0; c < 8; ++c) {  // k < 128: me from LDS tile
            bf16x8 av = *reinterpret_cast<const bf16x8*>(&tqm[ml * 136 + 16 * c + 8 * hi]);
            bf16x8 bv = ldbf8(wt2f + ((c * 4 + dt) * 64 + lane) * 8);
            g = MFMA32(av, bv, g);
        }
#pragma unroll
        for (int c = 8; c < 16; ++c) {  // k >= 128: query from global
            const float* p = query + (n0 + ml) * DD + 16 * (c - 8) + 8 * hi;
            float4 x0 = reinterpret_cast<const float4*>(p)[0];
            float4 x1 = reinterpret_cast<const float4*>(p)[1];
            AW av;
            av.u[0] = pk2(x0.x, x0.y); av.u[1] = pk2(x0.z, x0.w);
            av.u[2] = pk2(x1.x, x1.y); av.u[3] = pk2(x1.z, x1.w);
            bf16x8 bv = ldbf8(wt2f + ((c * 4 + dt) * 64 + lane) * 8);
            g = MFMA32(av.v, bv, g);
        }
        const float TWO_L2E = 2.88539008177792681472f;  // 2*log2(e)
        const int d = 32 * dt + ml;
        const float bias = bt2[d];
#pragma unroll
        for (int r = 0; r < 16; ++r) {
            int row = (r & 3) + 8 * (r >> 2) + 4 * hi;
            float x = g[r] + bias;
            float gt = 1.0f - 2.0f / (__builtin_amdgcn_exp2f(x * TWO_L2E) + 1.0f);
            float qv = query[(n0 + row) * DD + d];
            float mv = bfl(tqm[row * 136 + d]);
            out[(n0 + row) * DD + d] = qv + gt * (mv - qv);
        }
    }
}

// ---------------------------------------------------------------------------
extern "C" void kernel_launch(void* const* d_in, const int* in_sizes, int n_in,
                              void* d_out, int out_size, void* d_ws, size_t ws_size,
                              hipStream_t stream) {
    const float* query = (const float*)d_in[0];   // [N,128]
    const float* wt    = (const float*)d_in[1];   // [128,128]
    const float* bt    = (const float*)d_in[2];   // [128]
    const float* miw   = (const float*)d_in[3];   // [M,128]
    const float* mw    = (const float*)d_in[4];   // [M,128]
    const float* wt2   = (const float*)d_in[5];   // [128,256]
    const float* bt2   = (const float*)d_in[6];   // [128]

    float* out    = (float*)d_out;                // output 0: [N,128]
    float* me_out = out + (size_t)NQ * DD;        // output 1: mem_emb [N,128]

    // workspace (bf16 fragment-packed arrays), ~1.2 MB
    unsigned short* minnA = (unsigned short*)d_ws;          // [M/32][8][64][8]
    unsigned short* mwB   = minnA + (size_t)MM * DD;        // [M/32][8][64][8]
    unsigned short* wtb   = mwB + (size_t)MM * DD;          // [128][128] row-major
    unsigned short* wt2f  = wtb + (size_t)DD * DD;          // [16][4][64][8]

    k01_prep<<<112, 256, 0, stream>>>(miw, mw, wt, wt2, minnA, mwB, wtb, wt2f);
    k3_fused<<<NQ / 32, 256, 0, stream>>>(query, wtb, bt, minnA, mwB, wt2f, bt2,
                                          me_out, out);
}

// Round 9
// 47.583 us; speedup vs baseline: 2.7993x; 1.0110x over previous
//
#include <hip/hip_runtime.h>
#include <hip/hip_bf16.h>

#define NQ 16384
#define MM 2048
#define DD 128

typedef __attribute__((ext_vector_type(8))) short bf16x8;
typedef __attribute__((ext_vector_type(4))) float f32x4;
typedef __attribute__((ext_vector_type(16))) float f32x16;

#define MFMA16(a, b, c) __builtin_amdgcn_mfma_f32_16x16x32_bf16((a), (b), (c), 0, 0, 0)
#define MFMA32(a, b, c) __builtin_amdgcn_mfma_f32_32x32x16_bf16((a), (b), (c), 0, 0, 0)

static __device__ __forceinline__ unsigned short f2bf(float x) {
    union { __hip_bfloat16 h; unsigned short u; } cv;
    cv.h = __float2bfloat16(x);
    return cv.u;
}
static __device__ __forceinline__ unsigned pk2(float a, float b) {
    return (unsigned)f2bf(a) | ((unsigned)f2bf(b) << 16);
}
static __device__ __forceinline__ float bfl(unsigned u) {
    union { unsigned v; float f; } c; c.v = u << 16; return c.f;
}
static __device__ __forceinline__ float bfh(unsigned u) {
    union { unsigned v; float f; } c; c.v = u & 0xffff0000u; return c.f;
}
static __device__ __forceinline__ bf16x8 ldbf8(const unsigned short* p) {
    return *reinterpret_cast<const bf16x8*>(p);
}

union AW { unsigned u[4]; bf16x8 v; };

// ---------------------------------------------------------------------------
// K01: prep with FRAGMENT-ORDER packing (unchanged from r8).
// blocks 0..63 (one 32-m tile each): normalize memory_index_w rows and pack
//   into minnA[(tile*8+c)*64 + lane][8]; pack memory_w into
//   mwB[(tile*8+kc*4+dt)*64 + lane][8].
// blocks 64..111: W_t -> wtb (row-major bf16); W_t2 -> wt2f fragment order.
// ---------------------------------------------------------------------------
__global__ __launch_bounds__(256) void k01_prep(const float* __restrict__ miw,
                                                const float* __restrict__ mw,
                                                const float* __restrict__ wt,
                                                const float* __restrict__ wt2,
                                                unsigned short* __restrict__ minnA,
                                                unsigned short* __restrict__ mwB,
                                                unsigned short* __restrict__ wtb,
                                                unsigned short* __restrict__ wt2f) {
    int b = blockIdx.x;
    int t = threadIdx.x;
    if (b >= 64) {
        int i = (b - 64) * 1024 + t * 4;   // 48 blocks cover 49152 elems
        if (i < DD * DD) {
            float4 x = *reinterpret_cast<const float4*>(wt + i);
            *reinterpret_cast<uint2*>(wtb + i) = make_uint2(pk2(x.x, x.y), pk2(x.z, x.w));
        } else {
            int j = i - DD * DD;           // index into wt2 [128][256]
            float4 x = *reinterpret_cast<const float4*>(wt2 + j);
            int row = j >> 8, col = j & 255;
            unsigned short* dst = wt2f +
                (((((col >> 4) * 4 + (row >> 5)) * 64) + ((col >> 3) & 1) * 32 + (row & 31)) << 3) +
                (col & 7);
            dst[0] = f2bf(x.x); dst[1] = f2bf(x.y); dst[2] = f2bf(x.z); dst[3] = f2bf(x.w);
        }
        return;
    }
    int r = t >> 3;              // tile row 0..31
    int e = t & 7;               // 16-col group 0..7
    int m = b * 32 + r;

    float v[16];
    float ss = 0.f;
#pragma unroll
    for (int k = 0; k < 4; ++k) {
        float4 x = reinterpret_cast<const float4*>(miw + m * DD + e * 16)[k];
        v[4 * k] = x.x; v[4 * k + 1] = x.y; v[4 * k + 2] = x.z; v[4 * k + 3] = x.w;
        ss += x.x * x.x + x.y * x.y + x.z * x.z + x.w * x.w;
    }
    ss += __shfl_xor(ss, 1); ss += __shfl_xor(ss, 2); ss += __shfl_xor(ss, 4);
    float sc = 1.0f / fmaxf(sqrtf(ss), 1e-8f);

    unsigned u0 = pk2(v[0] * sc, v[1] * sc), u1 = pk2(v[2] * sc, v[3] * sc);
    unsigned u2 = pk2(v[4] * sc, v[5] * sc), u3 = pk2(v[6] * sc, v[7] * sc);
    unsigned u4 = pk2(v[8] * sc, v[9] * sc), u5 = pk2(v[10] * sc, v[11] * sc);
    unsigned u6 = pk2(v[12] * sc, v[13] * sc), u7 = pk2(v[14] * sc, v[15] * sc);
    *reinterpret_cast<uint4*>(minnA + ((((b * 8 + e) * 64) + r) << 3)) = make_uint4(u0, u1, u2, u3);
    *reinterpret_cast<uint4*>(minnA + ((((b * 8 + e) * 64) + 32 + r) << 3)) = make_uint4(u4, u5, u6, u7);

    float w[16];
#pragma unroll
    for (int k = 0; k < 4; ++k) {
        float4 x = reinterpret_cast<const float4*>(mw + m * DD + e * 16)[k];
        w[4 * k] = x.x; w[4 * k + 1] = x.y; w[4 * k + 2] = x.z; w[4 * k + 3] = x.w;
    }
    int kc = r >> 4, hh = (r >> 3) & 1, jj = r & 7;
    unsigned short* base = mwB +
        ((((b * 8 + kc * 4 + (e >> 1)) * 64) + hh * 32 + (e & 1) * 16) << 3) + jj;
#pragma unroll
    for (int u = 0; u < 16; ++u) base[u << 3] = f2bf(w[u]);
}

// ---------------------------------------------------------------------------
// K3: fused transform + attention + gating.  64 q per block.
// Grid 256 x 512thr (8 waves = 2 q-halves x 4 m-quarters). The two q-half
// waves of one m-quarter read IDENTICAL minnA/mwB streams in near-lockstep
// -> L1 dedup halves L2 demand; unique traffic halves vs 32q blocks.
// Dense fragment-order streams, register double-buffer, no loop barriers.
// Epilogue: bf16 LDS reduction across m-quarters per q-half, fused gating.
// ---------------------------------------------------------------------------
__global__ __launch_bounds__(512, 2) void k3_fused(const float* __restrict__ query,
                                                   const unsigned short* __restrict__ wtb,
                                                   const float* __restrict__ bt,
                                                   const unsigned short* __restrict__ minnA,
                                                   const unsigned short* __restrict__ mwB,
                                                   const unsigned short* __restrict__ wt2f,
                                                   const float* __restrict__ bt2,
                                                   float* __restrict__ me_out,
                                                   float* __restrict__ out) {
    // [0,52224): 6 reduction slots (2 qh x 3) of 8704 B
    // [52224,69632): tqm 64 rows x 136 shorts (tq_n, later me tile)
    __shared__ __align__(16) char pool[69632];
    unsigned short* tqm = reinterpret_cast<unsigned short*>(pool + 52224);

    const int lane = threadIdx.x & 63;
    const int wid = threadIdx.x >> 6;   // 0..7
    const int qh = wid >> 2;            // q-half (32 q)
    const int mq = wid & 3;             // m-quarter
    const int ml = lane & 31;
    const int hi = lane >> 5;
    const int n0 = blockIdx.x * 64;
    const float L2E = 1.44269504088896340736f;

    // ---- Phase 0: transform 64 q (waves 0..3, 16 q each), tq pre-scaled L2E
    if (wid < 4) {
        const int nl = lane & 15;
        const int g = lane >> 4;
        const int qb = n0 + 16 * wid;
        AW aq[4];
#pragma unroll
        for (int c = 0; c < 4; ++c) {
            const float* p = query + (qb + nl) * DD + 32 * c + 8 * g;
            float4 x0 = reinterpret_cast<const float4*>(p)[0];
            float4 x1 = reinterpret_cast<const float4*>(p)[1];
            aq[c].u[0] = pk2(x0.x, x0.y); aq[c].u[1] = pk2(x0.z, x0.w);
            aq[c].u[2] = pk2(x1.x, x1.y); aq[c].u[3] = pk2(x1.z, x1.w);
        }
        f32x4 acc[8];
#pragma unroll
        for (int t = 0; t < 8; ++t) acc[t] = (f32x4){0.f, 0.f, 0.f, 0.f};
#pragma unroll
        for (int t = 0; t < 8; ++t)
#pragma unroll
            for (int c = 0; c < 4; ++c) {
                bf16x8 bv = ldbf8(wtb + (16 * t + nl) * DD + 32 * c + 8 * g);
                acc[t] = MFMA16(aq[c].v, bv, acc[t]);
            }
        float ss[4] = {0.f, 0.f, 0.f, 0.f};
#pragma unroll
        for (int t = 0; t < 8; ++t) {
            float bias = bt[16 * t + nl];
#pragma unroll
            for (int r = 0; r < 4; ++r) {
                float vv = acc[t][r] + bias;
                acc[t][r] = vv;
                ss[r] += vv * vv;
            }
        }
#pragma unroll
        for (int r = 0; r < 4; ++r) {
            ss[r] += __shfl_xor(ss[r], 1);
            ss[r] += __shfl_xor(ss[r], 2);
            ss[r] += __shfl_xor(ss[r], 4);
            ss[r] += __shfl_xor(ss[r], 8);
        }
        float scl[4];
#pragma unroll
        for (int r = 0; r < 4; ++r) scl[r] = L2E / fmaxf(sqrtf(ss[r]), 1e-8f);
#pragma unroll
        for (int t = 0; t < 8; ++t)
#pragma unroll
            for (int r = 0; r < 4; ++r)
                tqm[(16 * wid + 4 * g + r) * 136 + 16 * t + nl] = f2bf(acc[t][r] * scl[r]);
    }
    __syncthreads();  // tq visible to all waves

    // Qn B-fragments for this wave's q-half (col n = ml, k = d)
    bf16x8 qn[8];
#pragma unroll
    for (int c = 0; c < 8; ++c)
        qn[c] = *reinterpret_cast<const bf16x8*>(&tqm[(32 * qh + ml) * 136 + 16 * c + 8 * hi]);

    const f32x16 zero16 = {0.f,0.f,0.f,0.f,0.f,0.f,0.f,0.f,0.f,0.f,0.f,0.f,0.f,0.f,0.f,0.f};
    f32x16 o[4];
#pragma unroll
    for (int t = 0; t < 4; ++t) o[t] = zero16;
    float den = 0.0f;

    const int mt0 = mq * 16;             // this quarter's 16-tile range
    const int rot = blockIdx.x & 15;

    bf16x8 aA[2][8], bw[2][8];
    {   // prologue: tile for it=0
        int ti = mt0 + rot;
#pragma unroll
        for (int c = 0; c < 8; ++c) aA[0][c] = ldbf8(minnA + ((ti * 8 + c) * 64 + lane) * 8);
#pragma unroll
        for (int q = 0; q < 8; ++q) bw[0][q] = ldbf8(mwB + ((ti * 8 + q) * 64 + lane) * 8);
    }

#pragma unroll 2
    for (int it = 0; it < 16; ++it) {
        const int cur = it & 1;
        // prefetch next tile's fragments (dense 1KB loads, independent regs)
        if (it < 15) {
            int tn = mt0 + ((it + 1 + rot) & 15);
#pragma unroll
            for (int c = 0; c < 8; ++c)
                aA[cur ^ 1][c] = ldbf8(minnA + ((tn * 8 + c) * 64 + lane) * 8);
#pragma unroll
            for (int q = 0; q < 8; ++q)
                bw[cur ^ 1][q] = ldbf8(mwB + ((tn * 8 + q) * 64 + lane) * 8);
        }

        // QK^T: D[m][n], two 4-deep accumulate chains over d
        f32x16 sA = zero16, sB = zero16;
#pragma unroll
        for (int c = 0; c < 4; ++c) sA = MFMA32(aA[cur][c], qn[c], sA);
#pragma unroll
        for (int c = 4; c < 8; ++c) sB = MFMA32(aA[cur][c], qn[c], sB);

        float p[16];
#pragma unroll
        for (int r = 0; r < 16; ++r)
            p[r] = __builtin_amdgcn_exp2f(sA[r] + sB[r]);
        {
            float e0 = (p[0] + p[1]) + (p[2] + p[3]);
            float e1 = (p[4] + p[5]) + (p[6] + p[7]);
            float e2 = (p[8] + p[9]) + (p[10] + p[11]);
            float e3 = (p[12] + p[13]) + (p[14] + p[15]);
            den += (e0 + e1) + (e2 + e3);
        }
        unsigned w0 = pk2(p[0], p[1]),   w1 = pk2(p[2], p[3]);
        unsigned w2 = pk2(p[4], p[5]),   w3 = pk2(p[6], p[7]);
        unsigned w4 = pk2(p[8], p[9]),   w5 = pk2(p[10], p[11]);
        unsigned w6 = pk2(p[12], p[13]), w7 = pk2(p[14], p[15]);
        auto r02 = __builtin_amdgcn_permlane32_swap(w0, w2, false, false);
        auto r13 = __builtin_amdgcn_permlane32_swap(w1, w3, false, false);
        auto r46 = __builtin_amdgcn_permlane32_swap(w4, w6, false, false);
        auto r57 = __builtin_amdgcn_permlane32_swap(w5, w7, false, false);
        AW a0, a1;
        a0.u[0] = r02[0]; a0.u[1] = r13[0]; a0.u[2] = r02[1]; a0.u[3] = r13[1];
        a1.u[0] = r46[0]; a1.u[1] = r57[0]; a1.u[2] = r46[1]; a1.u[3] = r57[1];
        // PV: a0 pairs kc=0 (bw[0..3] = dt 0..3), a1 pairs kc=1 (bw[4..7])
#pragma unroll
        for (int dt = 0; dt < 4; ++dt) {
            o[dt] = MFMA32(a0.v, bw[cur][dt], o[dt]);
            o[dt] = MFMA32(a1.v, bw[cur][4 + dt], o[dt]);
        }
    }

    // ---- cross-quarter reduction per q-half (bf16 partials + f32 den) ----
    if (mq >= 1) {
        char* dst = pool + (qh * 3 + (mq - 1)) * 8704 + lane * 136;
#pragma unroll
        for (int t = 0; t < 4; ++t) {
            unsigned u[8];
#pragma unroll
            for (int k = 0; k < 8; ++k) u[k] = pk2(o[t][2 * k], o[t][2 * k + 1]);
            *reinterpret_cast<uint4*>(dst + t * 32) = make_uint4(u[0], u[1], u[2], u[3]);
            *reinterpret_cast<uint4*>(dst + t * 32 + 16) = make_uint4(u[4], u[5], u[6], u[7]);
        }
        *reinterpret_cast<float*>(dst + 128) = den;
    }
    __syncthreads();
    if (mq == 0) {  // waves 0 (qh=0) and 4 (qh=1)
        for (int s = 0; s < 3; ++s) {
            const char* src = pool + (qh * 3 + s) * 8704 + lane * 136;
#pragma unroll
            for (int t = 0; t < 4; ++t) {
                uint4 ua = *reinterpret_cast<const uint4*>(src + t * 32);
                uint4 ub = *reinterpret_cast<const uint4*>(src + t * 32 + 16);
                unsigned u[8] = {ua.x, ua.y, ua.z, ua.w, ub.x, ub.y, ub.z, ub.w};
#pragma unroll
                for (int k = 0; k < 8; ++k) {
                    o[t][2 * k] += bfl(u[k]);
                    o[t][2 * k + 1] += bfh(u[k]);
                }
            }
            den += *reinterpret_cast<const float*>(src + 128);
        }
        den += __shfl_xor(den, 32);
        float invd = 1.0f / den;
        float inv[16];
#pragma unroll
        for (int r = 0; r < 16; ++r)
            inv[r] = __shfl(invd, (r & 3) + 8 * (r >> 2) + 4 * hi);
#pragma unroll
        for (int t = 0; t < 4; ++t)
#pragma unroll
            for (int r = 0; r < 16; ++r) {
                int row = 32 * qh + (r & 3) + 8 * (r >> 2) + 4 * hi;
                float me = o[t][r] * inv[r];
                me_out[(n0 + row) * DD + 32 * t + ml] = me;
                tqm[row * 136 + 32 * t + ml] = f2bf(me);  // me tile for gating
            }
    }
    __syncthreads();

    // ---- fused gating: G = tanh(cat(me,q) @ W_t2^T + b_t2); blend ----
    {
        const int qg = wid >> 2;  // q-half
        const int dt = wid & 3;   // d-tile 32*dt .. 32*dt+31
        f32x16 g = zero16;
#pragma unroll
        for (int c = 0; c < 8; ++c) {  // k < 128: me from LDS tile
            bf16x8 av = *reinterpret_cast<const bf16x8*>(
                &tqm[(32 * qg + ml) * 136 + 16 * c + 8 * hi]);
            bf16x8 bv = ldbf8(wt2f + ((c * 4 + dt) * 64 + lane) * 8);
            g = MFMA32(av, bv, g);
        }
#pragma unroll
        for (int c = 8; c < 16; ++c) {  // k >= 128: query from global
            const float* p = query + (n0 + 32 * qg + ml) * DD + 16 * (c - 8) + 8 * hi;
            float4 x0 = reinterpret_cast<const float4*>(p)[0];
            float4 x1 = reinterpret_cast<const float4*>(p)[1];
            AW av;
            av.u[0] = pk2(x0.x, x0.y); av.u[1] = pk2(x0.z, x0.w);
            av.u[2] = pk2(x1.x, x1.y); av.u[3] = pk2(x1.z, x1.w);
            bf16x8 bv = ldbf8(wt2f + ((c * 4 + dt) * 64 + lane) * 8);
            g = MFMA32(av.v, bv, g);
        }
        const float TWO_L2E = 2.88539008177792681472f;  // 2*log2(e)
        const int d = 32 * dt + ml;
        const float bias = bt2[d];
#pragma unroll
        for (int r = 0; r < 16; ++r) {
            int row = 32 * qg + (r & 3) + 8 * (r >> 2) + 4 * hi;
            float x = g[r] + bias;
            float gt = 1.0f - 2.0f / (__builtin_amdgcn_exp2f(x * TWO_L2E) + 1.0f);
            float qv = query[(n0 + row) * DD + d];
            float mv = bfl(tqm[row * 136 + d]);
            out[(n0 + row) * DD + d] = qv + gt * (mv - qv);
        }
    }
}

// ---------------------------------------------------------------------------
extern "C" void kernel_launch(void* const* d_in, const int* in_sizes, int n_in,
                              void* d_out, int out_size, void* d_ws, size_t ws_size,
                              hipStream_t stream) {
    const float* query = (const float*)d_in[0];   // [N,128]
    const float* wt    = (const float*)d_in[1];   // [128,128]
    const float* bt    = (const float*)d_in[2];   // [128]
    const float* miw   = (const float*)d_in[3];   // [M,128]
    const float* mw    = (const float*)d_in[4];   // [M,128]
    const float* wt2   = (const float*)d_in[5];   // [128,256]
    const float* bt2   = (const float*)d_in[6];   // [128]

    float* out    = (float*)d_out;                // output 0: [N,128]
    float* me_out = out + (size_t)NQ * DD;        // output 1: mem_emb [N,128]

    // workspace (bf16 fragment-packed arrays), ~1.2 MB
    unsigned short* minnA = (unsigned short*)d_ws;          // [M/32][8][64][8]
    unsigned short* mwB   = minnA + (size_t)MM * DD;        // [M/32][8][64][8]
    unsigned short* wtb   = mwB + (size_t)MM * DD;          // [128][128] row-major
    unsigned short* wt2f  = wtb + (size_t)DD * DD;          // [16][4][64][8]

    k01_prep<<<112, 256, 0, stream>>>(miw, mw, wt, wt2, minnA, mwB, wtb, wt2f);
    k3_fused<<<NQ / 64, 512, 0, stream>>>(query, wtb, bt, minnA, mwB, wt2f, bt2,
                                          me_out, out);
}